// Round 8
// baseline (1727.968 us; speedup 1.0000x reference)
//
#include <hip/hip_runtime.h>
#include <hip/hip_bf16.h>
#include <math.h>

#define NB 4096
#define NN 64
#define NM 4
#define NF 128
#define NOBS 64
#define ND 64
#define NH 4
#define NLAYER 2
#define NFF 128
#define NHID 64
#define NOUT 8
#define EPSC 1e-6f

typedef unsigned short ushort_t;
typedef __attribute__((ext_vector_type(8))) short short8v;   // 8 bf16 (4 VGPR) MFMA A/B frag
typedef __attribute__((ext_vector_type(4))) float f32x4;     // MFMA C/D frag

#define MFMA16(a, b, c) __builtin_amdgcn_mfma_f32_16x16x32_bf16((a), (b), (c), 0, 0, 0)

struct GParams {
    const float* x_anc; const float* g_anc; const float* x_nei; const float* ew_anc;
    const float* W_anc; const float* b_anc;
    const float* Wv_emb; const float* bv_emb; const float* Wv_val; const float* bv_val;
    const float* r_Win; const float* r_bin; const float* r_lng; const float* r_lnb;
    const float* r_W1; const float* r_b1; const float* r_W2; const float* r_b2;
    const float* r_Wview; const float* r_bview; const float* r_Wmode; const float* r_bmode;
    const float* log_tau;
    const float* L_Wq; const float* L_Wk; const float* L_Wv; const float* L_Wo;
    const float* L_ln1g; const float* L_ln1b; const float* L_ln2g; const float* L_ln2b;
    const float* L_Wf1; const float* L_bf1; const float* L_Wf2; const float* L_bf2;
    const float* p_lng; const float* p_lnb; const float* p_W1; const float* p_b1;
    const float* p_W2; const float* p_b2;
    const uint4* wsf;     // prepped split-bf16 weight fragments (see prep_w)
    float* out;
};

__device__ __forceinline__ float gelu_f(float x) {
    return 0.5f * x * (1.0f + erff(x * 0.7071067811865476f));
}
__device__ __forceinline__ float wsum64(float v) {
#pragma unroll
    for (int off = 32; off > 0; off >>= 1) v += __shfl_xor(v, off, 64);
    return v;
}
__device__ __forceinline__ float wmax64(float v) {
#pragma unroll
    for (int off = 32; off > 0; off >>= 1) v = fmaxf(v, __shfl_xor(v, off, 64));
    return v;
}
__device__ __forceinline__ float bf2f(ushort_t u) {
    union { unsigned int i; float f; } c; c.i = ((unsigned int)u) << 16; return c.f;
}
__device__ __forceinline__ ushort_t f2bf(float f) {
    __hip_bfloat16 h = __float2bfloat16(f);
    ushort_t u; __builtin_memcpy(&u, &h, 2); return u;
}
__device__ __forceinline__ short8v ld_frag(const uint4* p) {
    union { uint4 q; short8v v; } u; u.q = *p; return u.v;
}

// ---------------------------------------------------------------------------
// Weight prep (unchanged): split-bf16 MFMA B-fragments in d_ws.
// ---------------------------------------------------------------------------
__global__ void prep_w(const float* Wv_emb, const float* L_Wk, const float* L_Wv, uint4* ws)
{
    int task = blockIdx.x * 256 + threadIdx.x;    // 48 frags * 64 lanes = 3072
    if (task >= 3072) return;
    int lane = task & 63;
    int frag = task >> 6;                         // 0..47
    const float* src; int ks, ct; uint4 *dhi, *dlo;
    if (frag < 16) {                              // W0
        ks = frag >> 2; ct = frag & 3;
        src = Wv_emb;
        dhi = ws + (size_t)frag * 64 + lane;
        dlo = ws + 1024 + (size_t)frag * 64 + lane;
    } else {
        int g = frag - 16;                        // 0..31
        int matidx = g >> 3;                      // 0=K0 1=V0 2=K1 3=V1
        int fi = g & 7;
        ks = fi >> 2; ct = fi & 3;                // ks in {0,1}
        src = ((matidx & 1) ? L_Wv : L_Wk) + (size_t)(matidx >> 1) * (ND * ND);
        dhi = ws + 2048 + (size_t)matidx * 1024 + (size_t)fi * 64 + lane;
        dlo = dhi + 512;
    }
    union { ushort_t u[8]; uint4 q; } hi, lo;
#pragma unroll
    for (int i = 0; i < 8; i++) {
        int k = ks * 32 + (lane >> 4) * 8 + i;
        int d = ct * 16 + (lane & 15);
        float w = src[k * ND + d];
        ushort_t h = f2bf(w);
        hi.u[i] = h;
        lo.u[i] = f2bf(w - bf2f(h));
    }
    *dhi = hi.q;
    *dlo = lo.q;
}

// launch_bounds notes (measured): (256,4) clamps to 64 VGPR -> spills (662us);
// (256,2) only 2 blocks resident; (256,3) = 3 blocks/CU, no spill -> best.
// Round-5: cross-wave K-split regressed (LDS partials + barriers + spills).
// Round-7: deeper per-thread ILP neutral (245->255us) -> phases not load-ILP-bound.
// Round-8 hypothesis: every serial phase was `if (t<64)` = wave0 = SIMD0 (waves
// pinned round-robin to SIMDs). All resident blocks' serial phases contend for
// ONE SIMD -> VALUBusy ceiling ~25% (measured 24%). Fix: rotate the executing
// wave per serial phase so concurrent blocks spread across all 4 SIMDs.
__global__ __launch_bounds__(256, 3)
void gora_fused(GParams P)
{
    const int b = blockIdx.x;
    const int t = threadIdx.x;
    const int lane = t & 63;
    const int wave = t >> 6;

    // ---- LDS ~43.5 KB -> 3 blocks/CU ----
    __shared__ alignas(16) char u1buf[NN * NF * 2];  // 16 KB: xsf bf16 then hns f32 (swizzled)
    __shared__ float hv[NM][ND];
    __shared__ __hip_bfloat16 kb16[NN][ND + 2];      // 8.25KB K (padded rows: 66 elems)
    __shared__ __hip_bfloat16 vb16[NN][ND + 2];      // 8.25KB V
    __shared__ float ew_s[NN * NM];                  // raw masked ew  [n*4+m]
    __shared__ float winv[NM], wssum[NM];
    __shared__ float xa[NF];
    __shared__ float ga[NOBS];
    __shared__ float xw[NM][NF];
    __shared__ float pvc[NM][ND];
    __shared__ float hfin[NHID];
    __shared__ float pi_raw[NH * NM];
    __shared__ float pi_s[NH][NM];
    __shared__ float beta_s[NH];
    __shared__ float gate_s[NH][NN];
    __shared__ float xcur[ND];
    __shared__ float qv[ND];
    __shared__ float attn_s[NH][NN];
    __shared__ float ctx_s[ND];
    __shared__ float ffs[NFF];
    __shared__ float sA[ND];
    __shared__ float sB[ND];

    // ================= loads =================
    {
        float e = P.ew_anc[(size_t)b * NN * NM + t];   // 256 = N*M exactly
        ew_s[t] = (e > 0.0f) ? e : 0.0f;               // ew * (ew>0)
    }
    if (t < NF) xa[t] = P.x_anc[(size_t)b * NF + t];
    else if (t < NF + NOBS) ga[t - NF] = P.g_anc[(size_t)b * NOBS + (t - NF)];
    {
        // xsf swizzled store: elem (n,f) byte = n*256 + ((f>>3 ^ (n&15))<<4) + (f&7)*2
        const float4* xn4 = (const float4*)(P.x_nei + (size_t)b * NN * NF);
#pragma unroll
        for (int i = 0; i < 8; i++) {
            int i4 = t + i * 256;                      // 2048 float4 total
            float4 v4 = xn4[i4];
            __hip_bfloat162 p0, p1;
            p0.x = __float2bfloat16(v4.x); p0.y = __float2bfloat16(v4.y);
            p1.x = __float2bfloat16(v4.z); p1.y = __float2bfloat16(v4.w);
            int n = i4 >> 5;
            int c = (i4 >> 1) & 15;
            char* dstb = u1buf + n * 256 + ((c ^ (n & 15)) << 4) + (i4 & 1) * 8;
            ((__hip_bfloat162*)dstb)[0] = p0;
            ((__hip_bfloat162*)dstb)[1] = p1;
        }
    }
    __syncthreads();

    // ======== view-weight norms (wave0, t<4) + h_anc (wave1) ========
    if (t < NM) {
        float s = 0.0f;
        for (int n = 0; n < NN; n++) s += ew_s[n * NM + t];
        float c = fmaxf(s, EPSC);
        winv[t]  = 1.0f / c;
        wssum[t] = s / c;
    }
    if (wave == 1) {
        int d = lane;
        float a0 = P.b_anc[d], a1 = 0.f, a2 = 0.f, a3 = 0.f;
#pragma unroll
        for (int f = 0; f < NF; f += 4) {
            a0 += xa[f]     * P.W_anc[f * ND + d];
            a1 += xa[f + 1] * P.W_anc[(f + 1) * ND + d];
            a2 += xa[f + 2] * P.W_anc[(f + 2) * ND + d];
            a3 += xa[f + 3] * P.W_anc[(f + 3) * ND + d];
        }
        xcur[d] = (a0 + a1) + (a2 + a3);  // x = h_anc
    }
    __syncthreads();

    // ======== xw[m][f] = sum_n w[m,n] * x_nei[n,f]  (all waves) ========
    {
        int f = t & (NF - 1);
        int m0 = t >> 7;                  // wave-uniform (0 or 1)
        const int fc = f >> 3, fe = (f & 7) * 2;
        float a0 = 0.f, a1 = 0.f;
        for (int n = 0; n < NN; n++) {
            const ushort_t* xp = (const ushort_t*)(u1buf + n * 256 + ((fc ^ (n & 15)) << 4) + fe);
            float xv = bf2f(*xp);
            a0 += ew_s[n * NM + m0] * xv;
            a1 += ew_s[n * NM + m0 + 2] * xv;
        }
        xw[m0][f]     = a0 * winv[m0];
        xw[m0 + 2][f] = a1 * winv[m0 + 2];
    }

    // ======== h_nei A-fragments (read xsf BEFORE the overwrite barrier) ========
    short8v afr[4];
    {
        const int row = wave * 16 + (lane & 15);
        const int sub = lane >> 4;
#pragma unroll
        for (int ks = 0; ks < 4; ks++) {
            int c = ks * 4 + sub;
            afr[ks] = *(const short8v*)(u1buf + row * 256 + ((c ^ (row & 15)) << 4));
        }
    }
    __syncthreads();   // all xsf readers (xw + afr) done; xw visible below

    // ======== h_nei = xsf @ W0 + bv_emb[0] via MFMA; D -> hns (overlays xsf) ========
    {
        const int n0 = wave * 16;
        const int colb = lane & 15;
        const int rsub = lane >> 4;
#pragma unroll
        for (int ct = 0; ct < 4; ct++) {
            float bias = P.bv_emb[ct * 16 + colb];
            f32x4 c = {bias, bias, bias, bias};
#pragma unroll
            for (int ks = 0; ks < 4; ks++) {
                short8v bhi = ld_frag(P.wsf + (size_t)(ks * 4 + ct) * 64 + lane);
                short8v blo = ld_frag(P.wsf + 1024 + (size_t)(ks * 4 + ct) * 64 + lane);
                c = MFMA16(afr[ks], bhi, c);
                c = MFMA16(afr[ks], blo, c);
            }
#pragma unroll
            for (int e = 0; e < 4; e++) {
                int n = n0 + rsub * 4 + e;
                int d = ct * 16 + colb;
                *(float*)(u1buf + n * 256 + ((((d >> 2) ^ (n & 15))) << 4) + (d & 3) * 4) = c[e];
            }
        }
    }

    // ======== per_view_ctx: hv = xw@Wv_emb[m] + s*bv_emb ; pvc = hv@Wv_val[m] (all waves) ========
    {
        int m = wave, d = lane;
        float a0 = wssum[m] * P.bv_emb[m * ND + d], a1 = 0.f, a2 = 0.f, a3 = 0.f;
        const float* We = P.Wv_emb + (size_t)m * NF * ND;
#pragma unroll
        for (int f = 0; f < NF; f += 4) {
            a0 += xw[m][f]     * We[f * ND + d];
            a1 += xw[m][f + 1] * We[(f + 1) * ND + d];
            a2 += xw[m][f + 2] * We[(f + 2) * ND + d];
            a3 += xw[m][f + 3] * We[(f + 3) * ND + d];
        }
        hv[m][d] = (a0 + a1) + (a2 + a3);
    }
    __syncthreads();
    {
        int m = wave, d = lane;
        float a0 = wssum[m] * P.bv_val[m * ND + d], a1 = 0.f, a2 = 0.f, a3 = 0.f;
        const float* Wv = P.Wv_val + (size_t)m * ND * ND;
#pragma unroll
        for (int k = 0; k < ND; k += 4) {
            a0 += hv[m][k]     * Wv[k * ND + d];
            a1 += hv[m][k + 1] * Wv[(k + 1) * ND + d];
            a2 += hv[m][k + 2] * Wv[(k + 2) * ND + d];
            a3 += hv[m][k + 3] * Wv[(k + 3) * ND + d];
        }
        pvc[m][d] = (a0 + a1) + (a2 + a3);
    }
    __syncthreads();

    // ======== ctx_vec (wave2) ========
    if (wave == 2) sA[lane] = 0.25f * (pvc[0][lane] + pvc[1][lane] + pvc[2][lane] + pvc[3][lane]);
    __syncthreads();
    // ======== r-MLP: Win (wave3) ========
    if (wave == 3) {
        int d = lane;
        float a0 = P.r_bin[d], a1 = 0.f, a2 = 0.f, a3 = 0.f;
#pragma unroll
        for (int f = 0; f < NOBS; f += 4) {
            a0 += ga[f]     * P.r_Win[f * NHID + d];
            a1 += ga[f + 1] * P.r_Win[(f + 1) * NHID + d];
            a2 += ga[f + 2] * P.r_Win[(f + 2) * NHID + d];
            a3 += ga[f + 3] * P.r_Win[(f + 3) * NHID + d];
        }
#pragma unroll
        for (int f = 0; f < ND; f += 4) {
            a0 += sA[f]     * P.r_Win[(NOBS + f) * NHID + d];
            a1 += sA[f + 1] * P.r_Win[(NOBS + f + 1) * NHID + d];
            a2 += sA[f + 2] * P.r_Win[(NOBS + f + 2) * NHID + d];
            a3 += sA[f + 3] * P.r_Win[(NOBS + f + 3) * NHID + d];
        }
        float acc = (a0 + a1) + (a2 + a3);
        float mean = wsum64(acc) * (1.0f / 64.0f);
        float dv = acc - mean;
        float var = wsum64(dv * dv) * (1.0f / 64.0f);
        float xln = dv * rsqrtf(var + 1e-5f) * P.r_lng[d] + P.r_lnb[d];
        sB[d] = gelu_f(xln);
    }
    __syncthreads();
    // ======== r-MLP: W1 (wave0) ========
    if (wave == 0) {
        int d = lane;
        float a0 = P.r_b1[d], a1 = 0.f, a2 = 0.f, a3 = 0.f;
#pragma unroll
        for (int k = 0; k < NHID; k += 4) {
            a0 += sB[k]     * P.r_W1[k * NHID + d];
            a1 += sB[k + 1] * P.r_W1[(k + 1) * NHID + d];
            a2 += sB[k + 2] * P.r_W1[(k + 2) * NHID + d];
            a3 += sB[k + 3] * P.r_W1[(k + 3) * NHID + d];
        }
        sA[d] = gelu_f((a0 + a1) + (a2 + a3));
    }
    __syncthreads();
    // ======== r-MLP: W2 (wave1) ========
    if (wave == 1) {
        int d = lane;
        float a0 = P.r_b2[d], a1 = 0.f, a2 = 0.f, a3 = 0.f;
#pragma unroll
        for (int k = 0; k < NHID; k += 4) {
            a0 += sA[k]     * P.r_W2[k * NHID + d];
            a1 += sA[k + 1] * P.r_W2[(k + 1) * NHID + d];
            a2 += sA[k + 2] * P.r_W2[(k + 2) * NHID + d];
            a3 += sA[k + 3] * P.r_W2[(k + 3) * NHID + d];
        }
        hfin[d] = gelu_f((a0 + a1) + (a2 + a3));
    }
    __syncthreads();

    // ======== pi (wave2) / beta (wave3): in-wave K-split ========
    if (wave == 2) {                    // pi_raw = hfin @ r_Wview, 16 outs x 4-way K-split
        int out = lane & 15;
        int h = out >> 2, mm = out & 3;
        int kq = lane >> 4;             // 0..3
        float a0 = 0.f, a1 = 0.f;
#pragma unroll
        for (int i = 0; i < 16; i += 2) {
            int k = kq * 16 + i;
            a0 += hfin[k]     * P.r_Wview[(h * NHID + k) * NM + mm];
            a1 += hfin[k + 1] * P.r_Wview[(h * NHID + k + 1) * NM + mm];
        }
        float acc = a0 + a1;
        acc += __shfl_xor(acc, 16, 64);
        acc += __shfl_xor(acc, 32, 64);
        if (kq == 0) pi_raw[out] = acc + P.r_bview[h * NM + mm];
    } else if (wave == 3) {             // beta = sigmoid(hfin @ r_Wmode), 4 outs x 16-way
        int h = lane >> 4;
        int kq = lane & 15;
        float acc = 0.f;
#pragma unroll
        for (int i = 0; i < 4; i++) {
            int k = kq * 4 + i;
            acc += hfin[k] * P.r_Wmode[h * NHID + k];
        }
        acc += __shfl_xor(acc, 1, 64);
        acc += __shfl_xor(acc, 2, 64);
        acc += __shfl_xor(acc, 4, 64);
        acc += __shfl_xor(acc, 8, 64);
        if (kq == 0) beta_s[h] = 1.0f / (1.0f + expf(-(acc + P.r_bmode[h])));
    }
    __syncthreads();
    if (wave == 0 && lane < NH) {
        int h = lane;
        float mx = -1e30f;
        for (int mm = 0; mm < NM; mm++) mx = fmaxf(mx, pi_raw[h * NM + mm]);
        float s = 0.f, e[NM];
        for (int mm = 0; mm < NM; mm++) { e[mm] = expf(pi_raw[h * NM + mm] - mx); s += e[mm]; }
        for (int mm = 0; mm < NM; mm++) pi_s[h][mm] = e[mm] / s;
    }
    __syncthreads();

    // ======== gate[h][n] = log(sum_m pi[h,m]*ew_raw[n,m] + EPS)  (all waves) ========
    {
        int h = wave, n = lane;
        float wv = 0.f;
        for (int mm = 0; mm < NM; mm++) wv += pi_s[h][mm] * ew_s[n * NM + mm];
        gate_s[h][n] = logf(wv + EPSC);
    }
    __syncthreads();

    // ======== attention + FF layers ========
    const float inv_tau_scale = 0.25f / expf(P.log_tau[wave]);  // scale=1/sqrt(16)
#pragma unroll
    for (int l = 0; l < NLAYER; l++) {
        const float* Wq  = P.L_Wq  + l * ND * ND;
        const float* Wo  = P.L_Wo  + l * ND * ND;
        const float* ln1g = P.L_ln1g + l * ND;
        const float* ln1b = P.L_ln1b + l * ND;
        const float* ln2g = P.L_ln2g + l * ND;
        const float* ln2b = P.L_ln2b + l * ND;
        const float* Wf1 = P.L_Wf1 + l * ND * NFF;
        const float* bf1 = P.L_bf1 + l * NFF;
        const float* Wf2 = P.L_Wf2 + l * NFF * ND;
        const float* bf2 = P.L_bf2 + l * ND;
        // serial-phase wave rotation (see header comment)
        const int qw  = (l == 0) ? 0 : 2;   // qv
        const int pw  = (l == 0) ? 1 : 3;   // PV
        const int ow  = (l == 0) ? 2 : 0;   // Wo + LN1
        const int f1a = (l == 0) ? 3 : 1;   // FF1 low half
        const int f1b = (l == 0) ? 0 : 2;   // FF1 high half
        const int fw  = (l == 0) ? 1 : 3;   // FF2 + LN2

        if (wave == qw) {
            int d = lane;
            float a0 = 0.f, a1 = 0.f, a2 = 0.f, a3 = 0.f;
#pragma unroll
            for (int k = 0; k < ND; k += 4) {
                a0 += xcur[k]     * Wq[k * ND + d];
                a1 += xcur[k + 1] * Wq[(k + 1) * ND + d];
                a2 += xcur[k + 2] * Wq[(k + 2) * ND + d];
                a3 += xcur[k + 3] * Wq[(k + 3) * ND + d];
            }
            qv[d] = (a0 + a1) + (a2 + a3);
        }
        // ---- K/V projections via MFMA (all waves) ----
        {
            const int n0 = wave * 16;
            const int row = n0 + (lane & 15);
            const int rsub = lane >> 4;
            short8v ahi[2], alo[2];
#pragma unroll
            for (int ks = 0; ks < 2; ks++) {
                int c0 = ks * 8 + rsub * 2;
                f32x4 x0 = *(const f32x4*)(u1buf + row * 256 + ((c0 ^ (row & 15)) << 4));
                f32x4 x1 = *(const f32x4*)(u1buf + row * 256 + (((c0 + 1) ^ (row & 15)) << 4));
                union { ushort_t u[8]; short8v v; } uh, ul;
#pragma unroll
                for (int i = 0; i < 8; i++) {
                    float w = (i < 4) ? x0[i] : x1[i - 4];
                    ushort_t h = f2bf(w);
                    uh.u[i] = h;
                    ul.u[i] = f2bf(w - bf2f(h));
                }
                ahi[ks] = uh.v; alo[ks] = ul.v;
            }
            const uint4* bbase = P.wsf + 2048 + (size_t)(l * 2) * 1024;
#pragma unroll
            for (int mat = 0; mat < 2; mat++) {           // 0 = K, 1 = V
                const uint4* bb = bbase + (size_t)mat * 1024;
                __hip_bfloat16* dst = mat ? &vb16[0][0] : &kb16[0][0];
#pragma unroll
                for (int ct = 0; ct < 4; ct++) {
                    f32x4 c = {0.f, 0.f, 0.f, 0.f};
#pragma unroll
                    for (int ks = 0; ks < 2; ks++) {
                        short8v bhi = ld_frag(bb + (size_t)(ks * 4 + ct) * 64 + lane);
                        short8v blo = ld_frag(bb + 512 + (size_t)(ks * 4 + ct) * 64 + lane);
                        c = MFMA16(ahi[ks], bhi, c);
                        c = MFMA16(ahi[ks], blo, c);
                        c = MFMA16(alo[ks], bhi, c);
                    }
#pragma unroll
                    for (int e = 0; e < 4; e++) {
                        int n = n0 + rsub * 4 + e;
                        dst[n * (ND + 2) + ct * 16 + (lane & 15)] = __float2bfloat16(c[e]);
                    }
                }
            }
        }
        __syncthreads();
        // scores + softmax over n (one head per wave, all waves); K read as 8x bf16x2
        {
            int h = wave, n = lane;
            const __hip_bfloat162* kp = (const __hip_bfloat162*)&kb16[n][h * 16];
            float s = 0.f;
#pragma unroll
            for (int j = 0; j < 8; j++) {
                float2 kf = __bfloat1622float2(kp[j]);
                s += qv[h * 16 + 2 * j] * kf.x + qv[h * 16 + 2 * j + 1] * kf.y;
            }
            s = s * inv_tau_scale + gate_s[h][n];
            float mx = wmax64(s);
            float e = expf(s - mx);
            float se = wsum64(e);
            attn_s[h][n] = e / se;
        }
        __syncthreads();
        if (wave == pw) {
            int d = lane;
            int h = d >> 4;
            float a0 = 0.f, a1 = 0.f, a2 = 0.f, a3 = 0.f;
#pragma unroll
            for (int n = 0; n < NN; n += 4) {
                a0 += attn_s[h][n]     * __bfloat162float(vb16[n][d]);
                a1 += attn_s[h][n + 1] * __bfloat162float(vb16[n + 1][d]);
                a2 += attn_s[h][n + 2] * __bfloat162float(vb16[n + 2][d]);
                a3 += attn_s[h][n + 3] * __bfloat162float(vb16[n + 3][d]);
            }
            ctx_s[d] = (a0 + a1) + (a2 + a3);
        }
        __syncthreads();
        if (wave == ow) {
            int d = lane;
            float a0 = 0.f, a1 = 0.f, a2 = 0.f, a3 = 0.f;
#pragma unroll
            for (int c = 0; c < ND; c += 4) {
                a0 += ctx_s[c]     * Wo[c * ND + d];
                a1 += ctx_s[c + 1] * Wo[(c + 1) * ND + d];
                a2 += ctx_s[c + 2] * Wo[(c + 2) * ND + d];
                a3 += ctx_s[c + 3] * Wo[(c + 3) * ND + d];
            }
            float xv = xcur[d] + (a0 + a1) + (a2 + a3);
            float mean = wsum64(xv) * (1.0f / 64.0f);
            float dv = xv - mean;
            float var = wsum64(dv * dv) * (1.0f / 64.0f);
            xcur[d] = dv * rsqrtf(var + 1e-5f) * ln1g[d] + ln1b[d];
        }
        __syncthreads();
        if (wave == f1a || wave == f1b) {
            int j = ((wave == f1b) ? 64 : 0) + lane;
            float a0 = bf1[j], a1 = 0.f, a2 = 0.f, a3 = 0.f;
#pragma unroll
            for (int d = 0; d < ND; d += 4) {
                a0 += xcur[d]     * Wf1[d * NFF + j];
                a1 += xcur[d + 1] * Wf1[(d + 1) * NFF + j];
                a2 += xcur[d + 2] * Wf1[(d + 2) * NFF + j];
                a3 += xcur[d + 3] * Wf1[(d + 3) * NFF + j];
            }
            ffs[j] = gelu_f((a0 + a1) + (a2 + a3));
        }
        __syncthreads();
        if (wave == fw) {
            int d = lane;
            float a0 = bf2[d], a1 = 0.f, a2 = 0.f, a3 = 0.f;
#pragma unroll
            for (int j = 0; j < NFF; j += 4) {
                a0 += ffs[j]     * Wf2[j * ND + d];
                a1 += ffs[j + 1] * Wf2[(j + 1) * ND + d];
                a2 += ffs[j + 2] * Wf2[(j + 2) * ND + d];
                a3 += ffs[j + 3] * Wf2[(j + 3) * ND + d];
            }
            float xv = xcur[d] + (a0 + a1) + (a2 + a3);
            float mean = wsum64(xv) * (1.0f / 64.0f);
            float dv = xv - mean;
            float var = wsum64(dv * dv) * (1.0f / 64.0f);
            xcur[d] = dv * rsqrtf(var + 1e-5f) * ln2g[d] + ln2b[d];
        }
        __syncthreads();
    }

    // ======== blended + final head (waves 0,1,2 rotated) ========
    if (wave == 0) {
        int d = lane;
        float acc = 0.f;
#pragma unroll
        for (int h = 0; h < NH; h++) {
            float iso = 0.f;
#pragma unroll
            for (int mm = 0; mm < NM; mm++) iso += pi_s[h][mm] * pvc[mm][d];
            acc += (1.0f - beta_s[h]) * iso + beta_s[h] * xcur[d];
        }
        float bl = acc * 0.25f;
        float mean = wsum64(bl) * (1.0f / 64.0f);
        float dv = bl - mean;
        float var = wsum64(dv * dv) * (1.0f / 64.0f);
        sA[d] = dv * rsqrtf(var + 1e-5f) * P.p_lng[d] + P.p_lnb[d];
    }
    __syncthreads();
    if (wave == 1 && lane < 32) {
        int d = lane;
        float a0 = P.p_b1[d], a1 = 0.f, a2 = 0.f, a3 = 0.f;
#pragma unroll
        for (int k = 0; k < ND; k += 4) {
            a0 += sA[k]     * P.p_W1[k * 32 + d];
            a1 += sA[k + 1] * P.p_W1[(k + 1) * 32 + d];
            a2 += sA[k + 2] * P.p_W1[(k + 2) * 32 + d];
            a3 += sA[k + 3] * P.p_W1[(k + 3) * 32 + d];
        }
        sB[d] = gelu_f((a0 + a1) + (a2 + a3));
    }
    __syncthreads();
    if (wave == 2 && lane < NOUT) {
        int d = lane;
        float a0 = P.p_b2[d], a1 = 0.f;
#pragma unroll
        for (int j = 0; j < 32; j += 2) {
            a0 += sB[j]     * P.p_W2[j * NOUT + d];
            a1 += sB[j + 1] * P.p_W2[(j + 1) * NOUT + d];
        }
        P.out[(size_t)b * NOUT + d] = a0 + a1;
    }
}

extern "C" void kernel_launch(void* const* d_in, const int* in_sizes, int n_in,
                              void* d_out, int out_size, void* d_ws, size_t ws_size,
                              hipStream_t stream)
{
    (void)in_sizes; (void)n_in; (void)ws_size; (void)out_size;
    GParams P;
    P.x_anc   = (const float*)d_in[0];
    P.g_anc   = (const float*)d_in[1];
    P.x_nei   = (const float*)d_in[2];
    P.ew_anc  = (const float*)d_in[3];
    P.W_anc   = (const float*)d_in[4];
    P.b_anc   = (const float*)d_in[5];
    P.Wv_emb  = (const float*)d_in[6];
    P.bv_emb  = (const float*)d_in[7];
    P.Wv_val  = (const float*)d_in[8];
    P.bv_val  = (const float*)d_in[9];
    P.r_Win   = (const float*)d_in[10];
    P.r_bin   = (const float*)d_in[11];
    P.r_lng   = (const float*)d_in[12];
    P.r_lnb   = (const float*)d_in[13];
    P.r_W1    = (const float*)d_in[14];
    P.r_b1    = (const float*)d_in[15];
    P.r_W2    = (const float*)d_in[16];
    P.r_b2    = (const float*)d_in[17];
    P.r_Wview = (const float*)d_in[18];
    P.r_bview = (const float*)d_in[19];
    P.r_Wmode = (const float*)d_in[20];
    P.r_bmode = (const float*)d_in[21];
    P.log_tau = (const float*)d_in[22];
    P.L_Wq    = (const float*)d_in[23];
    P.L_Wk    = (const float*)d_in[24];
    P.L_Wv    = (const float*)d_in[25];
    P.L_Wo    = (const float*)d_in[26];
    P.L_ln1g  = (const float*)d_in[27];
    P.L_ln1b  = (const float*)d_in[28];
    P.L_ln2g  = (const float*)d_in[29];
    P.L_ln2b  = (const float*)d_in[30];
    P.L_Wf1   = (const float*)d_in[31];
    P.L_bf1   = (const float*)d_in[32];
    P.L_Wf2   = (const float*)d_in[33];
    P.L_bf2   = (const float*)d_in[34];
    P.p_lng   = (const float*)d_in[35];
    P.p_lnb   = (const float*)d_in[36];
    P.p_W1    = (const float*)d_in[37];
    P.p_b1    = (const float*)d_in[38];
    P.p_W2    = (const float*)d_in[39];
    P.p_b2    = (const float*)d_in[40];
    P.wsf     = (const uint4*)d_ws;
    P.out     = (float*)d_out;
    hipLaunchKernelGGL(prep_w, dim3(12), dim3(256), 0, stream,
                       P.Wv_emb, P.L_Wk, P.L_Wv, (uint4*)d_ws);
    hipLaunchKernelGGL(gora_fused, dim3(NB), dim3(256), 0, stream, P);
}